// Round 1
// baseline (968.341 us; speedup 1.0000x reference)
//
#include <hip/hip_runtime.h>

// ---------------------------------------------------------------------------
// TextGCN (2-layer GCN, eval mode) on MI355X.
// Key algebraic fusions:
//   * xw1_word = word @ (W_lin@W1) + (b_lin@W1)   -- never materialize [N,768] x
//   * layer-2 aggregation only for mask_idx nodes (10K instead of 100K)
// CSR-by-destination built once per call; both layers reuse it.
// ---------------------------------------------------------------------------

__global__ void k_fuse_w(const float* __restrict__ Wlin, const float* __restrict__ blin,
                         const float* __restrict__ W1, float* __restrict__ Wfuse,
                         float* __restrict__ bfuse) {
  int c = threadIdx.x;            // 64 threads = 64 output cols
  int r = blockIdx.x;             // 0..299 rows of Wfuse, block 300 = bfuse
  float acc = 0.f;
  if (r < 300) {
    const float* wl = Wlin + (size_t)r * 768;
    for (int k = 0; k < 768; ++k) acc += wl[k] * W1[k * 64 + c];
    Wfuse[r * 64 + c] = acc;
  } else {
    for (int k = 0; k < 768; ++k) acc += blin[k] * W1[k * 64 + c];
    bfuse[c] = acc;
  }
}

// deg (weighted, incl. self-loop weight 1) and cnt (in-degree incl. self loop)
__global__ void k_deg_cnt(const int* __restrict__ ei, const float* __restrict__ ew,
                          int E, int N, float* __restrict__ deg, int* __restrict__ cnt) {
  int t = blockIdx.x * blockDim.x + threadIdx.x;
  if (t < N) {
    atomicAdd(deg + t, 1.0f);   // self loop
    atomicAdd(cnt + t, 1);
  } else if (t < N + E) {
    int e = t - N;
    int c = ei[E + e];          // col = edge_index[1][e]
    atomicAdd(deg + c, ew[e]);
    atomicAdd(cnt + c, 1);
  }
}

__global__ void k_dis(const float* __restrict__ deg, float* __restrict__ dis, int N) {
  int i = blockIdx.x * blockDim.x + threadIdx.x;
  if (i < N) {
    float d = deg[i];
    dis[i] = d > 0.f ? rsqrtf(fmaxf(d, 1e-12f)) : 0.f;
  }
}

// ---- 3-kernel exclusive scan of cnt[N] -> offs[N+1] (chunk = 1024 elems) ----
__global__ void k_scan_reduce(const int* __restrict__ cnt, int N, int* __restrict__ bsum) {
  __shared__ int sd[256];
  int b = blockIdx.x, t = threadIdx.x;
  int base = b * 1024 + t * 4;
  int s = 0;
#pragma unroll
  for (int j = 0; j < 4; ++j) s += (base + j < N) ? cnt[base + j] : 0;
  sd[t] = s; __syncthreads();
  for (int off = 128; off > 0; off >>= 1) {
    if (t < off) sd[t] += sd[t + off];
    __syncthreads();
  }
  if (t == 0) bsum[b] = sd[0];
}

__global__ void k_scan_small(int* __restrict__ bsum, int nb) {
  __shared__ int s[128];
  int t = threadIdx.x;
  int v = (t < nb) ? bsum[t] : 0;
  s[t] = v; __syncthreads();
  for (int off = 1; off < 128; off <<= 1) {
    int x = (t >= off) ? s[t - off] : 0;
    __syncthreads();
    s[t] += x;
    __syncthreads();
  }
  if (t < nb) bsum[t] = s[t] - v;   // exclusive
}

__global__ void k_scan_final(const int* __restrict__ cnt, int N, const int* __restrict__ bsum,
                             int* __restrict__ offs, int* __restrict__ cursor) {
  __shared__ int sd[256];
  int b = blockIdx.x, t = threadIdx.x;
  int base = b * 1024 + t * 4;
  int v[4], loc = 0;
#pragma unroll
  for (int j = 0; j < 4; ++j) { v[j] = (base + j < N) ? cnt[base + j] : 0; loc += v[j]; }
  sd[t] = loc; __syncthreads();
  for (int off = 1; off < 256; off <<= 1) {
    int x = (t >= off) ? sd[t - off] : 0;
    __syncthreads();
    sd[t] += x;
    __syncthreads();
  }
  int run = bsum[b] + sd[t] - loc;  // exclusive prefix for this thread's 4 elems
#pragma unroll
  for (int j = 0; j < 4; ++j) {
    if (base + j < N) { offs[base + j] = run; cursor[base + j] = run; run += v[j]; }
  }
  if (b == gridDim.x - 1 && t == 255) offs[N] = run;  // total (OOB elems are 0)
}

// fill CSR entries: (src, norm) packed as int2, bucketed by destination col
__global__ void k_fill(const int* __restrict__ ei, const float* __restrict__ ew,
                       const float* __restrict__ dis, int E, int N,
                       int* __restrict__ cursor, int2* __restrict__ entries) {
  int t = blockIdx.x * blockDim.x + threadIdx.x;
  if (t < N) {                              // self loop: row=col=t, w=1
    int pos = atomicAdd(cursor + t, 1);
    float d = dis[t];
    entries[pos] = make_int2(t, __float_as_int(d * d));
  } else if (t < N + E) {
    int e = t - N;
    int r = ei[e], c = ei[E + e];
    int pos = atomicAdd(cursor + c, 1);
    entries[pos] = make_int2(r, __float_as_int(dis[r] * ew[e] * dis[c]));
  }
}

// tall-skinny GEMM: out[R,64] = X[R,K] @ W[K,64] (+bias). One wave = 8 rows,
// lane = output col. W reads coalesced (L2-resident), X reads wave-uniform.
template <int K, bool HAS_BIAS>
__global__ void k_mm(const float* __restrict__ X, const float* __restrict__ W,
                     const float* __restrict__ bias, float* __restrict__ out, int R) {
  const int lane = threadIdx.x & 63;
  const int wv = threadIdx.x >> 6;
  const int r0 = (blockIdx.x * 4 + wv) * 8;
  if (r0 >= R) return;
  float acc[8];
#pragma unroll
  for (int j = 0; j < 8; ++j) acc[j] = 0.f;
  const float* x0 = X + (size_t)r0 * K;
  for (int k = 0; k < K; k += 4) {
    float w0 = W[(k + 0) * 64 + lane];
    float w1 = W[(k + 1) * 64 + lane];
    float w2 = W[(k + 2) * 64 + lane];
    float w3 = W[(k + 3) * 64 + lane];
#pragma unroll
    for (int j = 0; j < 8; ++j) {
      float4 xv = *(const float4*)(x0 + (size_t)j * K + k);
      acc[j] += xv.x * w0;
      acc[j] += xv.y * w1;
      acc[j] += xv.z * w2;
      acc[j] += xv.w * w3;
    }
  }
  float b = HAS_BIAS ? bias[lane] : 0.f;
#pragma unroll
  for (int j = 0; j < 8; ++j) out[(size_t)(r0 + j) * 64 + lane] = acc[j] + b;
}

// aggregation: out[i][lane] = bias[lane] + sum_{(src,nw) in CSR[i]} xin[src][lane]*nw
__global__ void k_agg(const float* __restrict__ xin, const int2* __restrict__ entries,
                      const int* __restrict__ offs, const float* __restrict__ bias,
                      float* __restrict__ xout, int N, int relu) {
  const int lane = threadIdx.x & 63;
  const int wv = threadIdx.x >> 6;
  int i = blockIdx.x * 4 + wv;
  if (i >= N) return;
  int p = offs[i], pe = offs[i + 1];
  float acc = bias[lane];
  for (; p < pe; ++p) {
    int2 ent = entries[p];                         // wave-uniform
    acc += xin[(size_t)ent.x * 64 + lane] * __int_as_float(ent.y);
  }
  if (relu) acc = fmaxf(acc, 0.f);
  xout[(size_t)i * 64 + lane] = acc;
}

// layer-2 aggregation only for masked nodes; also emits y[mask] as float
__global__ void k_agg2(const float* __restrict__ xin, const int2* __restrict__ entries,
                       const int* __restrict__ offs, const float* __restrict__ bias,
                       const int* __restrict__ mask, const int* __restrict__ y,
                       float* __restrict__ out0, float* __restrict__ outY, int M) {
  const int lane = threadIdx.x & 63;
  const int wv = threadIdx.x >> 6;
  int o = blockIdx.x * 4 + wv;
  if (o >= M) return;
  int i = mask[o];
  int p = offs[i], pe = offs[i + 1];
  float acc = bias[lane];
  for (; p < pe; ++p) {
    int2 ent = entries[p];
    acc += xin[(size_t)ent.x * 64 + lane] * __int_as_float(ent.y);
  }
  out0[(size_t)o * 64 + lane] = acc;
  if (lane == 0) outY[o] = (float)y[i];
}

extern "C" void kernel_launch(void* const* d_in, const int* in_sizes, int n_in,
                              void* d_out, int out_size, void* d_ws, size_t ws_size,
                              hipStream_t stream) {
  const float* doc   = (const float*)d_in[0];
  const float* wordf = (const float*)d_in[1];
  const float* ew    = (const float*)d_in[2];
  const float* Wlin  = (const float*)d_in[3];
  const float* blin  = (const float*)d_in[4];
  const float* W1    = (const float*)d_in[5];
  const float* b1    = (const float*)d_in[6];
  const float* W2    = (const float*)d_in[7];
  const float* b2    = (const float*)d_in[8];
  const int*   ei    = (const int*)d_in[9];
  const int*   mask  = (const int*)d_in[10];
  const int*   y     = (const int*)d_in[11];

  const int E  = in_sizes[2];
  const int M  = in_sizes[10];
  const int ND = in_sizes[0] / 768;
  const int NW = in_sizes[1] / 300;
  const int N  = ND + NW;
  const int NE = N + E;

  // workspace carve (aligned 256B)
  char* p = (char*)d_ws;
  auto carve = [&](size_t bytes) -> void* {
    void* q = (void*)p;
    p += (bytes + 255) & ~(size_t)255;
    return q;
  };
  float* Wfuse  = (float*)carve(300 * 64 * 4);
  float* bfuse  = (float*)carve(64 * 4);
  float* deg    = (float*)carve((size_t)N * 4);
  float* dis    = (float*)carve((size_t)N * 4);
  int*   cnt    = (int*)carve((size_t)N * 4);
  int*   offs   = (int*)carve(((size_t)N + 1) * 4);
  int*   cursor = (int*)carve((size_t)N * 4);
  int*   bsum   = (int*)carve(1024);
  int2*  entries = (int2*)carve((size_t)NE * 8);
  float* xw1    = (float*)carve((size_t)N * 64 * 4);
  float* h1     = (float*)carve((size_t)N * 64 * 4);
  float* xw2    = xw1;  // xw1 dead after layer-1 aggregation; reuse

  hipMemsetAsync(deg, 0, (size_t)N * 4, stream);
  hipMemsetAsync(cnt, 0, (size_t)N * 4, stream);

  k_fuse_w<<<301, 64, 0, stream>>>(Wlin, blin, W1, Wfuse, bfuse);
  k_deg_cnt<<<(NE + 255) / 256, 256, 0, stream>>>(ei, ew, E, N, deg, cnt);
  k_dis<<<(N + 255) / 256, 256, 0, stream>>>(deg, dis, N);

  int nb = (N + 1023) / 1024;  // 98 for N=100000, fits single-block scan of 128
  k_scan_reduce<<<nb, 256, 0, stream>>>(cnt, N, bsum);
  k_scan_small<<<1, 128, 0, stream>>>(bsum, nb);
  k_scan_final<<<nb, 256, 0, stream>>>(cnt, N, bsum, offs, cursor);
  k_fill<<<(NE + 255) / 256, 256, 0, stream>>>(ei, ew, dis, E, N, cursor, entries);

  // layer-1 projection: doc rows use W1 (K=768); word rows use fused W (K=300)
  k_mm<768, false><<<ND / 32, 256, 0, stream>>>(doc, W1, nullptr, xw1, ND);
  k_mm<300, true><<<NW / 32, 256, 0, stream>>>(wordf, Wfuse, bfuse, xw1 + (size_t)ND * 64, NW);

  k_agg<<<(N + 3) / 4, 256, 0, stream>>>(xw1, entries, offs, b1, h1, N, 1);

  k_mm<64, false><<<N / 32, 256, 0, stream>>>(h1, W2, nullptr, xw2, N);

  float* out0 = (float*)d_out;
  float* outY = out0 + (size_t)M * 64;
  k_agg2<<<(M + 3) / 4, 256, 0, stream>>>(xw2, entries, offs, b2, mask, y, out0, outY, M);
}

// Round 2
// 538.822 us; speedup vs baseline: 1.7971x; 1.7971x over previous
//
#include <hip/hip_runtime.h>

// ---------------------------------------------------------------------------
// TextGCN (2-layer GCN, eval mode) on MI355X.
// Fusions:
//   * xw1_word = word @ (W_lin@W1) + (b_lin@W1)   -- never materialize [N,768] x
//   * layer 2: agg(h1@W2)[mask] == agg(h1)[mask] @ W2  -- aggregate-then-project,
//     kills the [100000,64]@[64,64] GEMM (only 10K masked rows projected)
// CSR-by-destination built once per call; both layers reuse it.
// ---------------------------------------------------------------------------

__global__ void k_fuse_w(const float* __restrict__ Wlin, const float* __restrict__ blin,
                         const float* __restrict__ W1, float* __restrict__ Wfuse,
                         float* __restrict__ bfuse) {
  int c = threadIdx.x;            // 64 threads = 64 output cols
  int r = blockIdx.x;             // 0..299 rows of Wfuse, block 300 = bfuse
  float acc = 0.f;
  if (r < 300) {
    const float* wl = Wlin + (size_t)r * 768;
    for (int k = 0; k < 768; ++k) acc += wl[k] * W1[k * 64 + c];
    Wfuse[r * 64 + c] = acc;
  } else {
    for (int k = 0; k < 768; ++k) acc += blin[k] * W1[k * 64 + c];
    bfuse[c] = acc;
  }
}

// deg (weighted, incl. self-loop weight 1) and cnt (in-degree incl. self loop)
__global__ void k_deg_cnt(const int* __restrict__ ei, const float* __restrict__ ew,
                          int E, int N, float* __restrict__ deg, int* __restrict__ cnt) {
  int t = blockIdx.x * blockDim.x + threadIdx.x;
  if (t < N) {
    atomicAdd(deg + t, 1.0f);   // self loop
    atomicAdd(cnt + t, 1);
  } else if (t < N + E) {
    int e = t - N;
    int c = ei[E + e];          // col = edge_index[1][e]
    atomicAdd(deg + c, ew[e]);
    atomicAdd(cnt + c, 1);
  }
}

__global__ void k_dis(const float* __restrict__ deg, float* __restrict__ dis, int N) {
  int i = blockIdx.x * blockDim.x + threadIdx.x;
  if (i < N) {
    float d = deg[i];
    dis[i] = d > 0.f ? rsqrtf(fmaxf(d, 1e-12f)) : 0.f;
  }
}

// ---- 3-kernel exclusive scan of cnt[N] -> offs[N+1] (chunk = 1024 elems) ----
__global__ void k_scan_reduce(const int* __restrict__ cnt, int N, int* __restrict__ bsum) {
  __shared__ int sd[256];
  int b = blockIdx.x, t = threadIdx.x;
  int base = b * 1024 + t * 4;
  int s = 0;
#pragma unroll
  for (int j = 0; j < 4; ++j) s += (base + j < N) ? cnt[base + j] : 0;
  sd[t] = s; __syncthreads();
  for (int off = 128; off > 0; off >>= 1) {
    if (t < off) sd[t] += sd[t + off];
    __syncthreads();
  }
  if (t == 0) bsum[b] = sd[0];
}

__global__ void k_scan_small(int* __restrict__ bsum, int nb) {
  __shared__ int s[128];
  int t = threadIdx.x;
  int v = (t < nb) ? bsum[t] : 0;
  s[t] = v; __syncthreads();
  for (int off = 1; off < 128; off <<= 1) {
    int x = (t >= off) ? s[t - off] : 0;
    __syncthreads();
    s[t] += x;
    __syncthreads();
  }
  if (t < nb) bsum[t] = s[t] - v;   // exclusive
}

__global__ void k_scan_final(const int* __restrict__ cnt, int N, const int* __restrict__ bsum,
                             int* __restrict__ offs, int* __restrict__ cursor) {
  __shared__ int sd[256];
  int b = blockIdx.x, t = threadIdx.x;
  int base = b * 1024 + t * 4;
  int v[4], loc = 0;
#pragma unroll
  for (int j = 0; j < 4; ++j) { v[j] = (base + j < N) ? cnt[base + j] : 0; loc += v[j]; }
  sd[t] = loc; __syncthreads();
  for (int off = 1; off < 256; off <<= 1) {
    int x = (t >= off) ? sd[t - off] : 0;
    __syncthreads();
    sd[t] += x;
    __syncthreads();
  }
  int run = bsum[b] + sd[t] - loc;  // exclusive prefix for this thread's 4 elems
#pragma unroll
  for (int j = 0; j < 4; ++j) {
    if (base + j < N) { offs[base + j] = run; cursor[base + j] = run; run += v[j]; }
  }
  if (b == gridDim.x - 1 && t == 255) offs[N] = run;  // total (OOB elems are 0)
}

// fill CSR entries: (src, norm) packed as int2, bucketed by destination col
__global__ void k_fill(const int* __restrict__ ei, const float* __restrict__ ew,
                       const float* __restrict__ dis, int E, int N,
                       int* __restrict__ cursor, int2* __restrict__ entries) {
  int t = blockIdx.x * blockDim.x + threadIdx.x;
  if (t < N) {                              // self loop: row=col=t, w=1
    int pos = atomicAdd(cursor + t, 1);
    float d = dis[t];
    entries[pos] = make_int2(t, __float_as_int(d * d));
  } else if (t < N + E) {
    int e = t - N;
    int r = ei[e], c = ei[E + e];
    int pos = atomicAdd(cursor + c, 1);
    entries[pos] = make_int2(r, __float_as_int(dis[r] * ew[e] * dis[c]));
  }
}

// ---------------------------------------------------------------------------
// Tiled SGEMM: out[R,64] = X[R,K] @ W[K,64] (+bias). 64x64 tile, BK=32.
// 256 threads; thread (tx,ty) computes 4x4 micro-tile rows ty*4.., cols tx*4..
// Xs stored transposed (stride 68 keeps ds_read_b128 16B-aligned, bank-clean).
// Requires K % 4 == 0 (for float4 global loads); zero-fills K/R tails.
// ---------------------------------------------------------------------------
template <bool HAS_BIAS>
__global__ __launch_bounds__(256)
void k_gemm64(const float* __restrict__ X, const float* __restrict__ W,
              const float* __restrict__ bias, float* __restrict__ out,
              int R, int K) {
  __shared__ float Xs[32][68];
  __shared__ float Ws[32][64];
  const int t = threadIdx.x;
  const int row0 = blockIdx.x * 64;
  const int tx = t & 15;          // col group
  const int ty = t >> 4;          // row group
  const int xr = t >> 3;          // staging: X row within tile (and +32)
  const int xk = (t & 7) << 2;    // staging: X k offset 0,4,...,28
  const int wc = (t & 15) << 2;   // staging: W col 0,4,...,60
  const int wk = t >> 4;          // staging: W k row (and +16)
  float acc[4][4] = {};

  for (int k0 = 0; k0 < K; k0 += 32) {
#pragma unroll
    for (int h = 0; h < 2; ++h) {
      int r = xr + h * 32;
      int gr = row0 + r;
      int gk = k0 + xk;
      float4 v = make_float4(0.f, 0.f, 0.f, 0.f);
      if (gr < R && gk < K) v = *(const float4*)(X + (size_t)gr * K + gk);
      Xs[xk + 0][r] = v.x;
      Xs[xk + 1][r] = v.y;
      Xs[xk + 2][r] = v.z;
      Xs[xk + 3][r] = v.w;
    }
#pragma unroll
    for (int h = 0; h < 2; ++h) {
      int kk = wk + h * 16;
      int gk = k0 + kk;
      float4 v = make_float4(0.f, 0.f, 0.f, 0.f);
      if (gk < K) v = *(const float4*)(W + (size_t)gk * 64 + wc);
      *(float4*)&Ws[kk][wc] = v;
    }
    __syncthreads();
#pragma unroll
    for (int kk = 0; kk < 32; ++kk) {
      float4 xa = *(const float4*)&Xs[kk][ty * 4];
      float4 wb = *(const float4*)&Ws[kk][tx * 4];
      acc[0][0] = fmaf(xa.x, wb.x, acc[0][0]);
      acc[0][1] = fmaf(xa.x, wb.y, acc[0][1]);
      acc[0][2] = fmaf(xa.x, wb.z, acc[0][2]);
      acc[0][3] = fmaf(xa.x, wb.w, acc[0][3]);
      acc[1][0] = fmaf(xa.y, wb.x, acc[1][0]);
      acc[1][1] = fmaf(xa.y, wb.y, acc[1][1]);
      acc[1][2] = fmaf(xa.y, wb.z, acc[1][2]);
      acc[1][3] = fmaf(xa.y, wb.w, acc[1][3]);
      acc[2][0] = fmaf(xa.z, wb.x, acc[2][0]);
      acc[2][1] = fmaf(xa.z, wb.y, acc[2][1]);
      acc[2][2] = fmaf(xa.z, wb.z, acc[2][2]);
      acc[2][3] = fmaf(xa.z, wb.w, acc[2][3]);
      acc[3][0] = fmaf(xa.w, wb.x, acc[3][0]);
      acc[3][1] = fmaf(xa.w, wb.y, acc[3][1]);
      acc[3][2] = fmaf(xa.w, wb.z, acc[3][2]);
      acc[3][3] = fmaf(xa.w, wb.w, acc[3][3]);
    }
    __syncthreads();
  }

  float b0 = 0.f, b1 = 0.f, b2 = 0.f, b3 = 0.f;
  if (HAS_BIAS) {
    b0 = bias[tx * 4 + 0]; b1 = bias[tx * 4 + 1];
    b2 = bias[tx * 4 + 2]; b3 = bias[tx * 4 + 3];
  }
#pragma unroll
  for (int i = 0; i < 4; ++i) {
    int gr = row0 + ty * 4 + i;
    if (gr < R) {
      float4 o;
      o.x = acc[i][0] + b0;
      o.y = acc[i][1] + b1;
      o.z = acc[i][2] + b2;
      o.w = acc[i][3] + b3;
      *(float4*)(out + (size_t)gr * 64 + tx * 4) = o;
    }
  }
}

// aggregation (all nodes): out[i][lane] = bias[lane] + sum xin[src][lane]*nw, relu
__global__ void k_agg(const float* __restrict__ xin, const int2* __restrict__ entries,
                      const int* __restrict__ offs, const float* __restrict__ bias,
                      float* __restrict__ xout, int N) {
  const int lane = threadIdx.x & 63;
  const int wv = threadIdx.x >> 6;
  int i = blockIdx.x * 4 + wv;
  if (i >= N) return;
  int p = offs[i], pe = offs[i + 1];
  float acc = bias[lane];
  for (; p + 4 <= pe; p += 4) {
    int2 e0 = entries[p + 0];
    int2 e1 = entries[p + 1];
    int2 e2 = entries[p + 2];
    int2 e3 = entries[p + 3];
    float x0 = xin[(size_t)e0.x * 64 + lane];
    float x1 = xin[(size_t)e1.x * 64 + lane];
    float x2 = xin[(size_t)e2.x * 64 + lane];
    float x3 = xin[(size_t)e3.x * 64 + lane];
    acc = fmaf(x0, __int_as_float(e0.y), acc);
    acc = fmaf(x1, __int_as_float(e1.y), acc);
    acc = fmaf(x2, __int_as_float(e2.y), acc);
    acc = fmaf(x3, __int_as_float(e3.y), acc);
  }
  for (; p < pe; ++p) {
    int2 e = entries[p];
    acc = fmaf(xin[(size_t)e.x * 64 + lane], __int_as_float(e.y), acc);
  }
  acc = fmaxf(acc, 0.f);
  xout[(size_t)i * 64 + lane] = acc;
}

// masked aggregation (no bias, no relu) + emit y[mask] as float
__global__ void k_agg2m(const float* __restrict__ xin, const int2* __restrict__ entries,
                        const int* __restrict__ offs, const int* __restrict__ mask,
                        const int* __restrict__ y, float* __restrict__ tout,
                        float* __restrict__ outY, int M) {
  const int lane = threadIdx.x & 63;
  const int wv = threadIdx.x >> 6;
  int o = blockIdx.x * 4 + wv;
  if (o >= M) return;
  int i = mask[o];
  int p = offs[i], pe = offs[i + 1];
  float acc = 0.f;
  for (; p + 4 <= pe; p += 4) {
    int2 e0 = entries[p + 0];
    int2 e1 = entries[p + 1];
    int2 e2 = entries[p + 2];
    int2 e3 = entries[p + 3];
    float x0 = xin[(size_t)e0.x * 64 + lane];
    float x1 = xin[(size_t)e1.x * 64 + lane];
    float x2 = xin[(size_t)e2.x * 64 + lane];
    float x3 = xin[(size_t)e3.x * 64 + lane];
    acc = fmaf(x0, __int_as_float(e0.y), acc);
    acc = fmaf(x1, __int_as_float(e1.y), acc);
    acc = fmaf(x2, __int_as_float(e2.y), acc);
    acc = fmaf(x3, __int_as_float(e3.y), acc);
  }
  for (; p < pe; ++p) {
    int2 e = entries[p];
    acc = fmaf(xin[(size_t)e.x * 64 + lane], __int_as_float(e.y), acc);
  }
  tout[(size_t)o * 64 + lane] = acc;
  if (lane == 0) outY[o] = (float)y[i];
}

extern "C" void kernel_launch(void* const* d_in, const int* in_sizes, int n_in,
                              void* d_out, int out_size, void* d_ws, size_t ws_size,
                              hipStream_t stream) {
  const float* doc   = (const float*)d_in[0];
  const float* wordf = (const float*)d_in[1];
  const float* ew    = (const float*)d_in[2];
  const float* Wlin  = (const float*)d_in[3];
  const float* blin  = (const float*)d_in[4];
  const float* W1    = (const float*)d_in[5];
  const float* b1    = (const float*)d_in[6];
  const float* W2    = (const float*)d_in[7];
  const float* b2    = (const float*)d_in[8];
  const int*   ei    = (const int*)d_in[9];
  const int*   mask  = (const int*)d_in[10];
  const int*   y     = (const int*)d_in[11];

  const int E  = in_sizes[2];
  const int M  = in_sizes[10];
  const int ND = in_sizes[0] / 768;
  const int NW = in_sizes[1] / 300;
  const int N  = ND + NW;
  const int NE = N + E;

  // workspace carve (aligned 256B)
  char* p = (char*)d_ws;
  auto carve = [&](size_t bytes) -> void* {
    void* q = (void*)p;
    p += (bytes + 255) & ~(size_t)255;
    return q;
  };
  float* Wfuse  = (float*)carve(300 * 64 * 4);
  float* bfuse  = (float*)carve(64 * 4);
  float* deg    = (float*)carve((size_t)N * 4);
  float* dis    = (float*)carve((size_t)N * 4);
  int*   cnt    = (int*)carve((size_t)N * 4);
  int*   offs   = (int*)carve(((size_t)N + 1) * 4);
  int*   cursor = (int*)carve((size_t)N * 4);
  int*   bsum   = (int*)carve(1024);
  int2*  entries = (int2*)carve((size_t)NE * 8);
  float* xw1    = (float*)carve((size_t)N * 64 * 4);
  float* h1     = (float*)carve((size_t)N * 64 * 4);
  float* tmask  = xw1;  // xw1 dead after k_agg; reuse for masked agg output

  hipMemsetAsync(deg, 0, (size_t)N * 4, stream);
  hipMemsetAsync(cnt, 0, (size_t)N * 4, stream);

  k_fuse_w<<<301, 64, 0, stream>>>(Wlin, blin, W1, Wfuse, bfuse);
  k_deg_cnt<<<(NE + 255) / 256, 256, 0, stream>>>(ei, ew, E, N, deg, cnt);
  k_dis<<<(N + 255) / 256, 256, 0, stream>>>(deg, dis, N);

  int nb = (N + 1023) / 1024;
  k_scan_reduce<<<nb, 256, 0, stream>>>(cnt, N, bsum);
  k_scan_small<<<1, 128, 0, stream>>>(bsum, nb);
  k_scan_final<<<nb, 256, 0, stream>>>(cnt, N, bsum, offs, cursor);
  k_fill<<<(NE + 255) / 256, 256, 0, stream>>>(ei, ew, dis, E, N, cursor, entries);

  // layer-1 projection: doc rows use W1 (K=768); word rows use fused W (K=300)
  k_gemm64<false><<<(ND + 63) / 64, 256, 0, stream>>>(doc, W1, nullptr, xw1, ND, 768);
  k_gemm64<true><<<(NW + 63) / 64, 256, 0, stream>>>(wordf, Wfuse, bfuse,
                                                     xw1 + (size_t)ND * 64, NW, 300);

  // layer-1 aggregation (+b1, relu)
  k_agg<<<(N + 3) / 4, 256, 0, stream>>>(xw1, entries, offs, b1, h1, N);

  // layer-2: aggregate masked nodes over h1, then project [M,64]@[64,64]+b2
  float* out0 = (float*)d_out;
  float* outY = out0 + (size_t)M * 64;
  k_agg2m<<<(M + 3) / 4, 256, 0, stream>>>(h1, entries, offs, mask, y, tmask, outY, M);
  k_gemm64<true><<<(M + 63) / 64, 256, 0, stream>>>(tmask, W2, b2, out0, M, 64);
}